// Round 1
// baseline (192.649 us; speedup 1.0000x reference)
//
#include <hip/hip_runtime.h>
#include <cstdint>

#define BB 4
#define CC 1024
#define DD 1024
#define HH 16
#define HD 64
#define NH3 3072

typedef __attribute__((ext_vector_type(8))) short short8;   // 8 x bf16 (4 VGPRs)
typedef __attribute__((ext_vector_type(4))) float f32x4;

#define MFMA16(a, b, c) __builtin_amdgcn_mfma_f32_16x16x32_bf16(a, b, c, 0, 0, 0)
#define EXP2 __builtin_amdgcn_exp2f

// async global->LDS, 16B per lane; LDS dest = uniform base + lane*16
__device__ __forceinline__ void glds16(const void* g, void* l) {
    __builtin_amdgcn_global_load_lds(
        (const __attribute__((address_space(1))) void*)g,
        (__attribute__((address_space(3))) void*)l, 16, 0, 0);
}

__device__ __forceinline__ ushort f2bf(float f) {
    union { float f; uint32_t u; } v; v.f = f;
    uint32_t r = v.u + 0x7FFF + ((v.u >> 16) & 1);   // round-to-nearest-even
    return (ushort)(r >> 16);
}

// pack two fp32 -> bf16x2 via v_perm_b32
__device__ __forceinline__ uint32_t pack2bf(float a, float b) {
    uint32_t ua = __float_as_uint(a), ub = __float_as_uint(b);
    ua += 0x7FFF + ((ua >> 16) & 1);
    ub += 0x7FFF + ((ub >> 16) & 1);
    return __builtin_amdgcn_perm(ua, ub, 0x03020706);  // lo16=bf(a), hi16=bf(b)
}

// ---------------------------------------------------------------------------
// prep: fused x->bf16 convert + w_qkv^T + w_proj^T (one launch)
// ---------------------------------------------------------------------------
__global__ __launch_bounds__(256)
void prep_kernel(const float* __restrict__ x, ushort* __restrict__ xbf,
                 const float* __restrict__ wqkv, ushort* __restrict__ wqkvT,
                 const float* __restrict__ wprj, ushort* __restrict__ wprjT)
{
    __shared__ float Ts[64 * 65];
    const int blk = blockIdx.x;
    const int t = threadIdx.x;

    if (blk < 4096) {
        int i = blk * 256 + t;
        float4 v = ((const float4*)x)[i];
        ushort4 o;
        o.x = f2bf(v.x); o.y = f2bf(v.y); o.z = f2bf(v.z); o.w = f2bf(v.w);
        ((ushort4*)xbf)[i] = o;
        return;
    }

    const float* in; ushort* outp; int K, N, n0, k0;
    if (blk < 4864) {
        int bx = blk - 4096;
        in = wqkv; outp = wqkvT; K = DD; N = NH3;
        n0 = (bx % 48) * 64; k0 = (bx / 48) * 64;
    } else {
        int bx = blk - 4864;
        in = wprj; outp = wprjT; K = DD; N = DD;
        n0 = (bx % 16) * 64; k0 = (bx / 16) * 64;
    }
    #pragma unroll
    for (int i = 0; i < 16; ++i) {
        int idx = t + i * 256;
        int r = idx >> 6, c = idx & 63;
        Ts[r * 65 + c] = in[(size_t)(k0 + r) * N + n0 + c];
    }
    __syncthreads();
    #pragma unroll
    for (int i = 0; i < 16; ++i) {
        int idx = t + i * 256;
        int rr = idx >> 6, cc = idx & 63;
        outp[(size_t)(n0 + rr) * K + k0 + cc] = f2bf(Ts[cc * 65 + rr]);
    }
}

// ---------------------------------------------------------------------------
// bf16 MFMA GEMM (2-barrier structure) -- now used only for the projection.
// MT=64 : 4 waves in 2x2, wave tile 32x64 (2x4 MFMA) -- 2x the blocks (TLP).
// ---------------------------------------------------------------------------
template<int MODE, int MT>
__global__ __launch_bounds__(256)
void gemm_bt(const ushort* __restrict__ A, const ushort* __restrict__ Bt,
             const float* __restrict__ bias, float* __restrict__ Cf,
             ushort* __restrict__ qb, ushort* __restrict__ kb, ushort* __restrict__ vtb,
             int M, int N, int K)
{
    constexpr int MI = MT / 32;               // M-dir MFMA tiles per wave
    __shared__ ushort As[2][MT * 32];
    __shared__ ushort Bs[2][128 * 32];

    const int tid = threadIdx.x;
    const int wid = tid >> 6, lane = tid & 63;
    const int quad = lane >> 4, l15 = lane & 15;
    const int m0 = blockIdx.y * MT, n0 = blockIdx.x * 128;
    const int wm = (wid >> 1) * (MT / 2), wn = (wid & 1) * 64;

    const int sr = lane >> 2;
    const int sc = lane & 3;

    // A staging: wave stages MT/4 rows (16 rows per glds)
    const int ar0 = wid * (MT / 4) + sr;
    const int acg0 = sc ^ ((ar0 >> 1) & 3);
    const int acg1 = sc ^ (((ar0 + 16) >> 1) & 3);
    const ushort* Ar0 = A + (size_t)(m0 + ar0) * K + acg0 * 8;
    const ushort* Ar1 = A + (size_t)(m0 + ar0 + 16) * K + acg1 * 8;   // MT=128 only
    // B staging: 128 rows, 2 glds per wave
    const int br0 = wid * 32 + sr;
    const int bcg0 = sc ^ ((br0 >> 1) & 3);
    const int bcg1 = sc ^ (((br0 + 16) >> 1) & 3);
    const ushort* Br0 = Bt + (size_t)(n0 + br0) * K + bcg0 * 8;
    const ushort* Br1 = Bt + (size_t)(n0 + br0 + 16) * K + bcg1 * 8;

    f32x4 acc[MI][4];
    #pragma unroll
    for (int i = 0; i < MI; ++i)
        #pragma unroll
        for (int j = 0; j < 4; ++j) acc[i][j] = (f32x4)(0.0f);

    glds16(Ar0, &As[0][(wid * (MT / 4)) * 32]);
    glds16(Br0, &Bs[0][(wid * 32) * 32]);
    if (MT == 128) glds16(Ar1, &As[0][(wid * 32 + 16) * 32]);
    glds16(Br1, &Bs[0][(wid * 32 + 16) * 32]);

    int buf = 0;
    for (int k0 = 0; k0 < K; k0 += 32) {
        __syncthreads();
        if (k0 + 32 < K) {
            const int kn = k0 + 32;
            glds16(Ar0 + kn, &As[buf ^ 1][(wid * (MT / 4)) * 32]);
            glds16(Br0 + kn, &Bs[buf ^ 1][(wid * 32) * 32]);
            if (MT == 128) glds16(Ar1 + kn, &As[buf ^ 1][(wid * 32 + 16) * 32]);
            glds16(Br1 + kn, &Bs[buf ^ 1][(wid * 32 + 16) * 32]);
        }

        short8 af[MI], bf[4];
        #pragma unroll
        for (int i = 0; i < MI; ++i) {
            int row = wm + i * 16 + l15;
            af[i] = *(const short8*)(&As[buf][row * 32 + (quad ^ ((row >> 1) & 3)) * 8]);
        }
        #pragma unroll
        for (int j = 0; j < 4; ++j) {
            int col = wn + j * 16 + l15;
            bf[j] = *(const short8*)(&Bs[buf][col * 32 + (quad ^ ((col >> 1) & 3)) * 8]);
        }
        #pragma unroll
        for (int i = 0; i < MI; ++i)
            #pragma unroll
            for (int j = 0; j < 4; ++j)
                acc[i][j] = MFMA16(af[i], bf[j], acc[i][j]);
        buf ^= 1;
    }

    if (MODE == 0) {
        #pragma unroll
        for (int i = 0; i < MI; ++i) {
            int row = m0 + wm + i * 16 + quad * 4;
            #pragma unroll
            for (int j = 0; j < 4; ++j) {
                int col = n0 + wn + j * 16 + l15;
                float bv = bias[col];
                #pragma unroll
                for (int r = 0; r < 4; ++r)
                    Cf[(size_t)(row + r) * N + col] = acc[i][j][r] + bv;
            }
        }
    } else {
        #pragma unroll
        for (int j = 0; j < 4; ++j) {
            int n = n0 + wn + j * 16 + l15;
            int three = n >> 10;
            int h = (n >> 6) & 15;
            int hd = n & 63;
            float scale = (three == 0) ? 0.1803368801f : 1.0f;  // 0.125*log2(e)
            float bv = bias[n];
            #pragma unroll
            for (int i = 0; i < MI; ++i) {
                int row = m0 + wm + i * 16 + quad * 4;
                #pragma unroll
                for (int r = 0; r < 4; ++r) {
                    int m = row + r;
                    int b = m >> 10, c = m & 1023;
                    ushort val = f2bf((acc[i][j][r] + bv) * scale);
                    if (three == 0)
                        qb[((size_t)((b * HH + h) * CC) + c) * HD + hd] = val;
                    else if (three == 1)
                        kb[((size_t)((b * HH + h) * CC) + c) * HD + hd] = val;
                    else
                        vtb[((size_t)((b * HH + h) * HD) + hd) * CC + c] = val;
                }
            }
        }
    }
}

// ---------------------------------------------------------------------------
// QKV GEMM, 256x256 tile, 8 waves (2M x 4N), BK=32, 4-deep LDS ring (128 KB),
// counted vmcnt (never drains to 0 in the main loop), setprio around MFMA.
// While computing K-tile kt: stage kt+3; before kt: vmcnt(8) keeps kt+1/kt+2
// in flight, s_barrier makes the per-wave vmcnt a block-global guarantee.
// QKV scatter epilogue (block-uniform q/k/v since n0 is a multiple of 256).
// ---------------------------------------------------------------------------
__global__ __launch_bounds__(512, 2)
void gemm_qkv256(const ushort* __restrict__ A, const ushort* __restrict__ Bt,
                 const float* __restrict__ bias,
                 ushort* __restrict__ qb, ushort* __restrict__ kb,
                 ushort* __restrict__ vtb)
{
    constexpr int K  = DD;        // 1024
    constexpr int KT = K / 32;    // 32 K-tiles
    __shared__ ushort lds[4][16384];   // 4 bufs x (A 256x32 | B 256x32) bf16

    const int tid = threadIdx.x;
    const int wid = tid >> 6, lane = tid & 63;
    const int quad = lane >> 4, l15 = lane & 15;
    const int m0 = blockIdx.y * 256, n0 = blockIdx.x * 256;
    const int wm = (wid >> 2) * 128, wn = (wid & 3) * 64;

    // staging: thread covers A rows {ra, ra+128} and B rows {ra, ra+128}, 16B each.
    // LDS linear (glds16: uniform base + lane*16); global col-group pre-swizzled
    // so that physical (row, p) holds logical (row, p ^ ((row>>1)&3)).
    const int sr = lane >> 2, sc = lane & 3;
    const int ra = wid * 16 + sr;
    const int cga = sc ^ ((ra >> 1) & 3);            // (ra+128) has same swizzle
    const ushort* Ap0 = A  + (size_t)(m0 + ra) * K + cga * 8;
    const ushort* Ap1 = Ap0 + (size_t)128 * K;
    const ushort* Bp0 = Bt + (size_t)(n0 + ra) * K + cga * 8;
    const ushort* Bp1 = Bp0 + (size_t)128 * K;
    const int sA0 = (wid * 16) * 32;
    const int sA1 = sA0 + 128 * 32;
    const int sB0 = 8192 + sA0;
    const int sB1 = 8192 + sA1;

#define QSTAGE(kt) do { ushort* lb_ = &lds[(kt) & 3][0]; const int ko_ = (kt) * 32; \
        glds16(Ap0 + ko_, lb_ + sA0); \
        glds16(Ap1 + ko_, lb_ + sA1); \
        glds16(Bp0 + ko_, lb_ + sB0); \
        glds16(Bp1 + ko_, lb_ + sB1); } while (0)

    f32x4 acc[8][4];
    #pragma unroll
    for (int i = 0; i < 8; ++i)
        #pragma unroll
        for (int j = 0; j < 4; ++j) acc[i][j] = (f32x4)(0.0f);

    QSTAGE(0); QSTAGE(1); QSTAGE(2);   // 12 loads in flight

#define QPHASE(kt, VMS, DOSTAGE) do { \
        asm volatile("s_waitcnt " VMS "\n\ts_barrier" ::: "memory"); \
        const ushort* ab_ = &lds[(kt) & 3][0]; \
        short8 af_[8], bf_[4]; \
        _Pragma("unroll") \
        for (int i = 0; i < 8; ++i) { \
            int row = wm + i * 16 + l15; \
            af_[i] = *(const short8*)(ab_ + row * 32 + (quad ^ ((row >> 1) & 3)) * 8); } \
        _Pragma("unroll") \
        for (int j = 0; j < 4; ++j) { \
            int col = wn + j * 16 + l15; \
            bf_[j] = *(const short8*)(ab_ + 8192 + col * 32 + (quad ^ ((col >> 1) & 3)) * 8); } \
        if (DOSTAGE) QSTAGE((kt) + 3); \
        __builtin_amdgcn_s_setprio(1); \
        _Pragma("unroll") \
        for (int i = 0; i < 8; ++i) \
            _Pragma("unroll") \
            for (int j = 0; j < 4; ++j) \
                acc[i][j] = MFMA16(af_[i], bf_[j], acc[i][j]); \
        __builtin_amdgcn_s_setprio(0); \
        __builtin_amdgcn_sched_barrier(0); \
    } while (0)

    #pragma unroll 4
    for (int kt = 0; kt < KT - 4; ++kt)        // kt = 0..27, stages kt+3 <= 30
        QPHASE(kt, "vmcnt(8)", true);
    QPHASE(KT - 4, "vmcnt(8)", true);          // kt=28, stages 31
    QPHASE(KT - 3, "vmcnt(8)", false);         // kt=29: in-flight 30,31 stay
    QPHASE(KT - 2, "vmcnt(4)", false);         // kt=30: 31 stays in flight
    QPHASE(KT - 1, "vmcnt(0)", false);         // kt=31: final drain

    // epilogue: QKV scatter; `three` is block-uniform (n0 multiple of 256)
    #pragma unroll
    for (int j = 0; j < 4; ++j) {
        int n = n0 + wn + j * 16 + l15;
        int three = n >> 10;
        int h = (n >> 6) & 15;
        int hd = n & 63;
        float scale = (three == 0) ? 0.1803368801f : 1.0f;  // 0.125*log2(e)
        float bv = bias[n];
        #pragma unroll
        for (int i = 0; i < 8; ++i) {
            int row = m0 + wm + i * 16 + quad * 4;
            #pragma unroll
            for (int r = 0; r < 4; ++r) {
                int m = row + r;
                int b = m >> 10, c = m & 1023;
                ushort val = f2bf((acc[i][j][r] + bv) * scale);
                if (three == 0)
                    qb[((size_t)((b * HH + h) * CC) + c) * HD + hd] = val;
                else if (three == 1)
                    kb[((size_t)((b * HH + h) * CC) + c) * HD + hd] = val;
                else
                    vtb[((size_t)((b * HH + h) * HD) + hd) * CC + c] = val;
            }
        }
    }
#undef QPHASE
#undef QSTAGE
}

// ---------------------------------------------------------------------------
// Flash attention v6: cross-tile software pipeline, ROLLED loop + LDS-offset
// rotation. Iter kt: prefetch K/V_{kt+1}; PV_{kt-1} (independent MFMA stream);
// S_kt -> exp -> pack -> P_kt. K dbuf, V triple-buf, P dbuf (wave-private).
// ---------------------------------------------------------------------------
__global__ __launch_bounds__(256)
void attn_mfma6(const ushort* __restrict__ qb, const ushort* __restrict__ kb,
                const ushort* __restrict__ vt, ushort* __restrict__ attnb)
{
    __shared__ ushort lds[2 * 4096 + 3 * 4096 + 2 * 9216];   // 76 KB
    const uint K0 = 0, K1 = 4096;
    const uint V0 = 8192, V1 = 12288, V2 = 16384;
    const uint P0 = 20480, P1 = 29696;

    const int tid = threadIdx.x;
    const int wid = tid >> 6, lane = tid & 63;
    const int quad = lane >> 4, l15 = lane & 15;
    const int bh = blockIdx.x & 63;          // bh-fastest: XCD L2 locality
    const int qt = blockIdx.x >> 6;
    const int q0 = qt * 128;
    const int b = bh >> 4, h = bh & 15;

    const ushort* Qp  = qb + ((size_t)bh * CC + q0) * HD;
    const ushort* Kp  = kb + (size_t)bh * CC * HD;
    const ushort* Vtp = vt + (size_t)bh * HD * CC;

    const int sr = lane >> 3;    // 0..7
    const int sc = lane & 7;     // chunk 0..7

    // Q fragments straight from global: B-operand [n=qrow][k=d], kt-invariant
    short8 qf[2][2];
    #pragma unroll
    for (int q2 = 0; q2 < 2; ++q2) {
        int row = wid * 32 + q2 * 16 + l15;
        #pragma unroll
        for (int s = 0; s < 2; ++s)
            qf[q2][s] = *(const short8*)(Qp + (size_t)row * HD + (s * 4 + quad) * 8);
    }

    // staging addresses (kt-invariant parts)
    const int kr = wid * 16 + sr;            // rows kr, kr+8
    const int cgA = sc ^ (kr & 7);
    const int cgB = sc ^ ((kr + 8) & 7);
    const ushort* Kr0 = Kp  + (size_t)kr * HD + cgA * 8;
    const ushort* Kr1 = Kp  + (size_t)(kr + 8) * HD + cgB * 8;
    const ushort* Vr0 = Vtp + (size_t)kr * CC + cgA * 8;
    const ushort* Vr1 = Vtp + (size_t)(kr + 8) * CC + cgB * 8;

    const uint stg0 = (wid * 16) * 64;       // LDS staging offsets within a buffer
    const uint stg1 = (wid * 16 + 8) * 64;

    // prologue: K_0 -> K0, V_0 -> V0
    glds16(Kr0, lds + K0 + stg0);
    glds16(Kr1, lds + K0 + stg1);
    glds16(Vr0, lds + V0 + stg0);
    glds16(Vr1, lds + V0 + stg1);

    f32x4 oacc[2][4];
    #pragma unroll
    for (int q2 = 0; q2 < 2; ++q2)
        #pragma unroll
        for (int hb = 0; hb < 4; ++hb) oacc[q2][hb] = (f32x4)(0.0f);
    float lsum[2] = {0.0f, 0.0f};

    uint ksC = K0, ksN = K1;
    uint vsP = V2, vsC = V0, vsN = V1;
    uint psC = P0, psP = P1;

    for (int kt = 0; kt < 16; ++kt) {
        __syncthreads();                      // K_kt, V_kt resident
        if (kt < 15) {                        // prefetch K/V_{kt+1}
            const int koff = (kt + 1) * 64;
            glds16(Kr0 + (size_t)koff * HD, lds + ksN + stg0);
            glds16(Kr1 + (size_t)koff * HD, lds + ksN + stg1);
            glds16(Vr0 + koff,              lds + vsN + stg0);
            glds16(Vr1 + koff,              lds + vsN + stg1);
        }

        if (kt > 0) {
            // PV_{kt-1}: O += P_{kt-1} @ V_{kt-1}  (independent of S_kt)
            short8 vf[4][2];
            #pragma unroll
            for (int hb = 0; hb < 4; ++hb) {
                int hr = hb * 16 + l15;
                vf[hb][0] = *(const short8*)(lds + vsP + hr * 64 + ((quad ^ (hr & 7)) * 8));
                vf[hb][1] = *(const short8*)(lds + vsP + hr * 64 + (((4 + quad) ^ (hr & 7)) * 8));
            }
            #pragma unroll
            for (int q2 = 0; q2 < 2; ++q2) {
                int row = wid * 32 + q2 * 16 + l15;
                short8 pf0 = *(const short8*)(lds + psP + row * 72 + quad * 8);
                short8 pf1 = *(const short8*)(lds + psP + row * 72 + 32 + quad * 8);
                #pragma unroll
                for (int hb = 0; hb < 4; ++hb) {
                    oacc[q2][hb] = MFMA16(pf0, vf[hb][0], oacc[q2][hb]);
                    oacc[q2][hb] = MFMA16(pf1, vf[hb][1], oacc[q2][hb]);
                }
            }
        }

        // S_kt = K @ Q^T : lane holds S[qrow=l15][key=kb2*16+quad*4+r]
        #pragma unroll
        for (int kb2 = 0; kb2 < 4; ++kb2) {
            int krow = kb2 * 16 + l15;
            short8 kf0 = *(const short8*)(lds + ksC + krow * 64 + ((quad ^ (krow & 7)) * 8));
            short8 kf1 = *(const short8*)(lds + ksC + krow * 64 + (((4 + quad) ^ (krow & 7)) * 8));
            #pragma unroll
            for (int q2 = 0; q2 < 2; ++q2) {
                f32x4 st = (f32x4)(0.0f);
                st = MFMA16(kf0, qf[q2][0], st);
                st = MFMA16(kf1, qf[q2][1], st);
                float p0 = EXP2(st[0]);
                float p1 = EXP2(st[1]);
                float p2 = EXP2(st[2]);
                float p3 = EXP2(st[3]);
                lsum[q2] += (p0 + p1) + (p2 + p3);
                int row = wid * 32 + q2 * 16 + l15;
                *(uint2*)(lds + psC + row * 72 + kb2 * 16 + quad * 4) =
                    make_uint2(pack2bf(p0, p1), pack2bf(p2, p3));
            }
        }

        // rotate buffers
        uint t = vsP; vsP = vsC; vsC = vsN; vsN = t;
        t = ksC; ksC = ksN; ksN = t;
        t = psP; psP = psC; psC = t;
    }

    // final PV_15: P_15 at psP, V_15 at vsP (post-rotation); no barrier needed
    {
        short8 vf[4][2];
        #pragma unroll
        for (int hb = 0; hb < 4; ++hb) {
            int hr = hb * 16 + l15;
            vf[hb][0] = *(const short8*)(lds + vsP + hr * 64 + ((quad ^ (hr & 7)) * 8));
            vf[hb][1] = *(const short8*)(lds + vsP + hr * 64 + (((4 + quad) ^ (hr & 7)) * 8));
        }
        #pragma unroll
        for (int q2 = 0; q2 < 2; ++q2) {
            int row = wid * 32 + q2 * 16 + l15;
            short8 pf0 = *(const short8*)(lds + psP + row * 72 + quad * 8);
            short8 pf1 = *(const short8*)(lds + psP + row * 72 + 32 + quad * 8);
            #pragma unroll
            for (int hb = 0; hb < 4; ++hb) {
                oacc[q2][hb] = MFMA16(pf0, vf[hb][0], oacc[q2][hb]);
                oacc[q2][hb] = MFMA16(pf1, vf[hb][1], oacc[q2][hb]);
            }
        }
    }

    // reduce lsum across the 4 quads (lanes sharing l15)
    #pragma unroll
    for (int q2 = 0; q2 < 2; ++q2) {
        lsum[q2] += __shfl_xor(lsum[q2], 16);
        lsum[q2] += __shfl_xor(lsum[q2], 32);
    }

    #pragma unroll
    for (int q2 = 0; q2 < 2; ++q2) {
        #pragma unroll
        for (int r = 0; r < 4; ++r) {
            float inv = 1.0f / __shfl(lsum[q2], (lane & 48) | (quad * 4 + r));
            int c = q0 + wid * 32 + q2 * 16 + quad * 4 + r;
            #pragma unroll
            for (int hb = 0; hb < 4; ++hb) {
                int d = h * 64 + hb * 16 + l15;
                attnb[((size_t)(b * CC + c)) * DD + d] = f2bf(oacc[q2][hb][r] * inv);
            }
        }
    }
}

// ---------------------------------------------------------------------------
extern "C" void kernel_launch(void* const* d_in, const int* in_sizes, int n_in,
                              void* d_out, int out_size, void* d_ws, size_t ws_size,
                              hipStream_t stream)
{
    (void)in_sizes; (void)n_in; (void)out_size; (void)ws_size;
    const float* x      = (const float*)d_in[0];
    const float* w_qkv  = (const float*)d_in[1];
    const float* b_qkv  = (const float*)d_in[2];
    const float* w_proj = (const float*)d_in[3];
    const float* b_proj = (const float*)d_in[4];
    float* out = (float*)d_out;

    ushort* p = (ushort*)d_ws;
    ushort* xbf   = p;  p += (size_t)4 * 1024 * 1024;   // x bf16
    ushort* wqkvT = p;  p += (size_t)3 * 1024 * 1024;   // w_qkv^T bf16
    ushort* wprjT = p;  p += (size_t)1 * 1024 * 1024;   // w_proj^T bf16
    ushort* qbuf  = p;  p += (size_t)4 * 1024 * 1024;   // Q (B,H,C,Hd), pre-scaled
    ushort* kbuf  = p;  p += (size_t)4 * 1024 * 1024;   // K (B,H,C,Hd)
    ushort* vtb   = p;  p += (size_t)4 * 1024 * 1024;   // V^T (B,H,Hd,C)
    ushort* attnb = p;  p += (size_t)4 * 1024 * 1024;   // attention out (B,C,D)

    prep_kernel<<<5120, 256, 0, stream>>>(x, xbf, w_qkv, wqkvT, w_proj, wprjT);

    // QKV: 256x256 tile, 8 waves, 4-deep counted-vmcnt pipeline; grid 12x16=192
    gemm_qkv256<<<dim3(NH3 / 256, (BB * CC) / 256), 512, 0, stream>>>(
        xbf, wqkvT, b_qkv, qbuf, kbuf, vtb);

    attn_mfma6<<<512, 256, 0, stream>>>(qbuf, kbuf, vtb, attnb);

    // proj: M-tile 64 -> 512 blocks (2 blocks/CU) for latency hiding
    gemm_bt<0, 64><<<dim3(DD / 128, (BB * CC) / 64), 256, 0, stream>>>(
        attnb, wprjT, b_proj, out, nullptr, nullptr, nullptr, BB * CC, DD, DD);
}

// Round 2
// 190.959 us; speedup vs baseline: 1.0088x; 1.0088x over previous
//
#include <hip/hip_runtime.h>
#include <cstdint>

#define BB 4
#define CC 1024
#define DD 1024
#define HH 16
#define HD 64
#define NH3 3072

typedef __attribute__((ext_vector_type(8))) short short8;   // 8 x bf16 (4 VGPRs)
typedef __attribute__((ext_vector_type(4))) float f32x4;

#define MFMA16(a, b, c) __builtin_amdgcn_mfma_f32_16x16x32_bf16(a, b, c, 0, 0, 0)
#define EXP2 __builtin_amdgcn_exp2f

// async global->LDS, 16B per lane; LDS dest = uniform base + lane*16
__device__ __forceinline__ void glds16(const void* g, void* l) {
    __builtin_amdgcn_global_load_lds(
        (const __attribute__((address_space(1))) void*)g,
        (__attribute__((address_space(3))) void*)l, 16, 0, 0);
}

__device__ __forceinline__ ushort f2bf(float f) {
    union { float f; uint32_t u; } v; v.f = f;
    uint32_t r = v.u + 0x7FFF + ((v.u >> 16) & 1);   // round-to-nearest-even
    return (ushort)(r >> 16);
}

// pack two fp32 -> bf16x2 via v_perm_b32
__device__ __forceinline__ uint32_t pack2bf(float a, float b) {
    uint32_t ua = __float_as_uint(a), ub = __float_as_uint(b);
    ua += 0x7FFF + ((ua >> 16) & 1);
    ub += 0x7FFF + ((ub >> 16) & 1);
    return __builtin_amdgcn_perm(ua, ub, 0x03020706);  // lo16=bf(a), hi16=bf(b)
}

// ---------------------------------------------------------------------------
// prep: fused x->bf16 convert + w_qkv^T + w_proj^T (one launch)
// ---------------------------------------------------------------------------
__global__ __launch_bounds__(256)
void prep_kernel(const float* __restrict__ x, ushort* __restrict__ xbf,
                 const float* __restrict__ wqkv, ushort* __restrict__ wqkvT,
                 const float* __restrict__ wprj, ushort* __restrict__ wprjT)
{
    __shared__ float Ts[64 * 65];
    const int blk = blockIdx.x;
    const int t = threadIdx.x;

    if (blk < 4096) {
        int i = blk * 256 + t;
        float4 v = ((const float4*)x)[i];
        ushort4 o;
        o.x = f2bf(v.x); o.y = f2bf(v.y); o.z = f2bf(v.z); o.w = f2bf(v.w);
        ((ushort4*)xbf)[i] = o;
        return;
    }

    const float* in; ushort* outp; int K, N, n0, k0;
    if (blk < 4864) {
        int bx = blk - 4096;
        in = wqkv; outp = wqkvT; K = DD; N = NH3;
        n0 = (bx % 48) * 64; k0 = (bx / 48) * 64;
    } else {
        int bx = blk - 4864;
        in = wprj; outp = wprjT; K = DD; N = DD;
        n0 = (bx % 16) * 64; k0 = (bx / 16) * 64;
    }
    #pragma unroll
    for (int i = 0; i < 16; ++i) {
        int idx = t + i * 256;
        int r = idx >> 6, c = idx & 63;
        Ts[r * 65 + c] = in[(size_t)(k0 + r) * N + n0 + c];
    }
    __syncthreads();
    #pragma unroll
    for (int i = 0; i < 16; ++i) {
        int idx = t + i * 256;
        int rr = idx >> 6, cc = idx & 63;
        outp[(size_t)(n0 + rr) * K + k0 + cc] = f2bf(Ts[cc * 65 + rr]);
    }
}

// ---------------------------------------------------------------------------
// bf16 MFMA GEMM (2-barrier structure) -- used only for the projection.
// MT=64 : 4 waves in 2x2, wave tile 32x64 (2x4 MFMA) -- 2x the blocks (TLP).
// ---------------------------------------------------------------------------
template<int MODE, int MT>
__global__ __launch_bounds__(256)
void gemm_bt(const ushort* __restrict__ A, const ushort* __restrict__ Bt,
             const float* __restrict__ bias, float* __restrict__ Cf,
             ushort* __restrict__ qb, ushort* __restrict__ kb, ushort* __restrict__ vtb,
             int M, int N, int K)
{
    constexpr int MI = MT / 32;               // M-dir MFMA tiles per wave
    __shared__ ushort As[2][MT * 32];
    __shared__ ushort Bs[2][128 * 32];

    const int tid = threadIdx.x;
    const int wid = tid >> 6, lane = tid & 63;
    const int quad = lane >> 4, l15 = lane & 15;
    const int m0 = blockIdx.y * MT, n0 = blockIdx.x * 128;
    const int wm = (wid >> 1) * (MT / 2), wn = (wid & 1) * 64;

    const int sr = lane >> 2;
    const int sc = lane & 3;

    // A staging: wave stages MT/4 rows (16 rows per glds)
    const int ar0 = wid * (MT / 4) + sr;
    const int acg0 = sc ^ ((ar0 >> 1) & 3);
    const int acg1 = sc ^ (((ar0 + 16) >> 1) & 3);
    const ushort* Ar0 = A + (size_t)(m0 + ar0) * K + acg0 * 8;
    const ushort* Ar1 = A + (size_t)(m0 + ar0 + 16) * K + acg1 * 8;   // MT=128 only
    // B staging: 128 rows, 2 glds per wave
    const int br0 = wid * 32 + sr;
    const int bcg0 = sc ^ ((br0 >> 1) & 3);
    const int bcg1 = sc ^ (((br0 + 16) >> 1) & 3);
    const ushort* Br0 = Bt + (size_t)(n0 + br0) * K + bcg0 * 8;
    const ushort* Br1 = Bt + (size_t)(n0 + br0 + 16) * K + bcg1 * 8;

    f32x4 acc[MI][4];
    #pragma unroll
    for (int i = 0; i < MI; ++i)
        #pragma unroll
        for (int j = 0; j < 4; ++j) acc[i][j] = (f32x4)(0.0f);

    glds16(Ar0, &As[0][(wid * (MT / 4)) * 32]);
    glds16(Br0, &Bs[0][(wid * 32) * 32]);
    if (MT == 128) glds16(Ar1, &As[0][(wid * 32 + 16) * 32]);
    glds16(Br1, &Bs[0][(wid * 32 + 16) * 32]);

    int buf = 0;
    for (int k0 = 0; k0 < K; k0 += 32) {
        __syncthreads();
        if (k0 + 32 < K) {
            const int kn = k0 + 32;
            glds16(Ar0 + kn, &As[buf ^ 1][(wid * (MT / 4)) * 32]);
            glds16(Br0 + kn, &Bs[buf ^ 1][(wid * 32) * 32]);
            if (MT == 128) glds16(Ar1 + kn, &As[buf ^ 1][(wid * 32 + 16) * 32]);
            glds16(Br1 + kn, &Bs[buf ^ 1][(wid * 32 + 16) * 32]);
        }

        short8 af[MI], bf[4];
        #pragma unroll
        for (int i = 0; i < MI; ++i) {
            int row = wm + i * 16 + l15;
            af[i] = *(const short8*)(&As[buf][row * 32 + (quad ^ ((row >> 1) & 3)) * 8]);
        }
        #pragma unroll
        for (int j = 0; j < 4; ++j) {
            int col = wn + j * 16 + l15;
            bf[j] = *(const short8*)(&Bs[buf][col * 32 + (quad ^ ((col >> 1) & 3)) * 8]);
        }
        #pragma unroll
        for (int i = 0; i < MI; ++i)
            #pragma unroll
            for (int j = 0; j < 4; ++j)
                acc[i][j] = MFMA16(af[i], bf[j], acc[i][j]);
        buf ^= 1;
    }

    if (MODE == 0) {
        #pragma unroll
        for (int i = 0; i < MI; ++i) {
            int row = m0 + wm + i * 16 + quad * 4;
            #pragma unroll
            for (int j = 0; j < 4; ++j) {
                int col = n0 + wn + j * 16 + l15;
                float bv = bias[col];
                #pragma unroll
                for (int r = 0; r < 4; ++r)
                    Cf[(size_t)(row + r) * N + col] = acc[i][j][r] + bv;
            }
        }
    } else {
        #pragma unroll
        for (int j = 0; j < 4; ++j) {
            int n = n0 + wn + j * 16 + l15;
            int three = n >> 10;
            int h = (n >> 6) & 15;
            int hd = n & 63;
            float scale = (three == 0) ? 0.1803368801f : 1.0f;  // 0.125*log2(e)
            float bv = bias[n];
            #pragma unroll
            for (int i = 0; i < MI; ++i) {
                int row = m0 + wm + i * 16 + quad * 4;
                #pragma unroll
                for (int r = 0; r < 4; ++r) {
                    int m = row + r;
                    int b = m >> 10, c = m & 1023;
                    ushort val = f2bf((acc[i][j][r] + bv) * scale);
                    if (three == 0)
                        qb[((size_t)((b * HH + h) * CC) + c) * HD + hd] = val;
                    else if (three == 1)
                        kb[((size_t)((b * HH + h) * CC) + c) * HD + hd] = val;
                    else
                        vtb[((size_t)((b * HH + h) * HD) + hd) * CC + c] = val;
                }
            }
        }
    }
}

// ---------------------------------------------------------------------------
// QKV GEMM, 256x256 tile, 8 waves (2M x 4N), BK=32, 4-deep LDS ring (128 KB),
// counted vmcnt + 4-phase interleave (T3+T4+T5):
//   iter top: s_waitcnt vmcnt(8); s_barrier   (tile kt resident; kt+1,kt+2 in flight)
//   phase q (C-quadrant mh=q>>1, nh=q&1):
//     ds_read only first-needed frags (6/2/4/0; A/B frags reg-cached across phases)
//     issue 1 of 4 next-tile global_load_lds
//     sched_barrier; s_barrier; setprio(1); 8 MFMA; setprio(0); sched_barrier
// One wave's MFMA burst overlaps the SIMD-sibling wave's read/stage burst.
// Epilogue drains vmcnt 8 -> 8 -> 4 -> 0 across the last 3 iters.
// ---------------------------------------------------------------------------
__global__ __launch_bounds__(512, 2)
void gemm_qkv256(const ushort* __restrict__ A, const ushort* __restrict__ Bt,
                 const float* __restrict__ bias,
                 ushort* __restrict__ qb, ushort* __restrict__ kb,
                 ushort* __restrict__ vtb)
{
    constexpr int K  = DD;        // 1024
    constexpr int KT = K / 32;    // 32 K-tiles
    __shared__ ushort lds[4][16384];   // 4 bufs x (A 256x32 | B 256x32) bf16

    const int tid = threadIdx.x;
    const int wid = tid >> 6, lane = tid & 63;
    const int quad = lane >> 4, l15 = lane & 15;
    const int m0 = blockIdx.y * 256, n0 = blockIdx.x * 256;
    const int wm = (wid >> 2) * 128, wn = (wid & 3) * 64;

    // staging: thread covers A rows {ra, ra+128} and B rows {ra, ra+128}, 16B each.
    // LDS linear (glds16: uniform base + lane*16); global col-group pre-swizzled
    // so that physical (row, p) holds logical (row, p ^ ((row>>1)&3)).
    const int sr = lane >> 2, sc = lane & 3;
    const int ra = wid * 16 + sr;
    const int cga = sc ^ ((ra >> 1) & 3);            // (ra+128) has same swizzle
    const ushort* Ap0 = A  + (size_t)(m0 + ra) * K + cga * 8;
    const ushort* Ap1 = Ap0 + (size_t)128 * K;
    const ushort* Bp0 = Bt + (size_t)(n0 + ra) * K + cga * 8;
    const ushort* Bp1 = Bp0 + (size_t)128 * K;
    const int sA0 = (wid * 16) * 32;
    const int sA1 = sA0 + 128 * 32;
    const int sB0 = 8192 + sA0;
    const int sB1 = 8192 + sA1;

#define QSTAGE(kt) do { ushort* lb_ = &lds[(kt) & 3][0]; const int ko_ = (kt) * 32; \
        glds16(Ap0 + ko_, lb_ + sA0); \
        glds16(Ap1 + ko_, lb_ + sA1); \
        glds16(Bp0 + ko_, lb_ + sB0); \
        glds16(Bp1 + ko_, lb_ + sB1); } while (0)

    f32x4 acc[8][4];
    #pragma unroll
    for (int i = 0; i < 8; ++i)
        #pragma unroll
        for (int j = 0; j < 4; ++j) acc[i][j] = (f32x4)(0.0f);

    QSTAGE(0); QSTAGE(1); QSTAGE(2);   // 12 loads in flight

#define SCHED0 __builtin_amdgcn_sched_barrier(0)

#define QITER(kt, VMS, DOSTAGE) do { \
        asm volatile("s_waitcnt " VMS "\n\ts_barrier" ::: "memory"); \
        const ushort* ab_ = &lds[(kt) & 3][0]; \
        ushort* nb_ = &lds[((kt) + 3) & 3][0]; \
        const int ko_ = ((kt) + 3) * 32; \
        short8 a0_[4], a1_[4], b0_[2], b1_[2]; \
        /* phase 0: quadrant (mh0,nh0): read A0(4)+B0(2), stage Ap0 */ \
        _Pragma("unroll") \
        for (int i = 0; i < 4; ++i) { int row = wm + i * 16 + l15; \
            a0_[i] = *(const short8*)(ab_ + row * 32 + (quad ^ ((row >> 1) & 3)) * 8); } \
        _Pragma("unroll") \
        for (int j = 0; j < 2; ++j) { int col = wn + j * 16 + l15; \
            b0_[j] = *(const short8*)(ab_ + 8192 + col * 32 + (quad ^ ((col >> 1) & 3)) * 8); } \
        if (DOSTAGE) glds16(Ap0 + ko_, nb_ + sA0); \
        SCHED0; __builtin_amdgcn_s_barrier(); \
        __builtin_amdgcn_s_setprio(1); \
        _Pragma("unroll") \
        for (int i = 0; i < 4; ++i) \
            _Pragma("unroll") \
            for (int j = 0; j < 2; ++j) \
                acc[i][j] = MFMA16(a0_[i], b0_[j], acc[i][j]); \
        __builtin_amdgcn_s_setprio(0); SCHED0; \
        /* phase 1: quadrant (mh0,nh1): read B1(2), stage Ap1 */ \
        _Pragma("unroll") \
        for (int j = 0; j < 2; ++j) { int col = wn + (2 + j) * 16 + l15; \
            b1_[j] = *(const short8*)(ab_ + 8192 + col * 32 + (quad ^ ((col >> 1) & 3)) * 8); } \
        if (DOSTAGE) glds16(Ap1 + ko_, nb_ + sA1); \
        SCHED0; __builtin_amdgcn_s_barrier(); \
        __builtin_amdgcn_s_setprio(1); \
        _Pragma("unroll") \
        for (int i = 0; i < 4; ++i) \
            _Pragma("unroll") \
            for (int j = 0; j < 2; ++j) \
                acc[i][2 + j] = MFMA16(a0_[i], b1_[j], acc[i][2 + j]); \
        __builtin_amdgcn_s_setprio(0); SCHED0; \
        /* phase 2: quadrant (mh1,nh0): read A1(4), stage Bp0 */ \
        _Pragma("unroll") \
        for (int i = 0; i < 4; ++i) { int row = wm + (4 + i) * 16 + l15; \
            a1_[i] = *(const short8*)(ab_ + row * 32 + (quad ^ ((row >> 1) & 3)) * 8); } \
        if (DOSTAGE) glds16(Bp0 + ko_, nb_ + sB0); \
        SCHED0; __builtin_amdgcn_s_barrier(); \
        __builtin_amdgcn_s_setprio(1); \
        _Pragma("unroll") \
        for (int i = 0; i < 4; ++i) \
            _Pragma("unroll") \
            for (int j = 0; j < 2; ++j) \
                acc[4 + i][j] = MFMA16(a1_[i], b0_[j], acc[4 + i][j]); \
        __builtin_amdgcn_s_setprio(0); SCHED0; \
        /* phase 3: quadrant (mh1,nh1): no reads, stage Bp1 */ \
        if (DOSTAGE) glds16(Bp1 + ko_, nb_ + sB1); \
        SCHED0; __builtin_amdgcn_s_barrier(); \
        __builtin_amdgcn_s_setprio(1); \
        _Pragma("unroll") \
        for (int i = 0; i < 4; ++i) \
            _Pragma("unroll") \
            for (int j = 0; j < 2; ++j) \
                acc[4 + i][2 + j] = MFMA16(a1_[i], b1_[j], acc[4 + i][2 + j]); \
        __builtin_amdgcn_s_setprio(0); SCHED0; \
    } while (0)

    #pragma unroll 4
    for (int kt = 0; kt < KT - 4; ++kt)        // kt = 0..27, stages kt+3 <= 30
        QITER(kt, "vmcnt(8)", true);
    QITER(KT - 4, "vmcnt(8)", true);           // kt=28, stages 31
    QITER(KT - 3, "vmcnt(8)", false);          // kt=29: 30,31 stay in flight
    QITER(KT - 2, "vmcnt(4)", false);          // kt=30: 31 stays in flight
    QITER(KT - 1, "vmcnt(0)", false);          // kt=31: final drain

    // epilogue: QKV scatter; `three` is block-uniform (n0 multiple of 256)
    #pragma unroll
    for (int j = 0; j < 4; ++j) {
        int n = n0 + wn + j * 16 + l15;
        int three = n >> 10;
        int h = (n >> 6) & 15;
        int hd = n & 63;
        float scale = (three == 0) ? 0.1803368801f : 1.0f;  // 0.125*log2(e)
        float bv = bias[n];
        #pragma unroll
        for (int i = 0; i < 8; ++i) {
            int row = m0 + wm + i * 16 + quad * 4;
            #pragma unroll
            for (int r = 0; r < 4; ++r) {
                int m = row + r;
                int b = m >> 10, c = m & 1023;
                ushort val = f2bf((acc[i][j][r] + bv) * scale);
                if (three == 0)
                    qb[((size_t)((b * HH + h) * CC) + c) * HD + hd] = val;
                else if (three == 1)
                    kb[((size_t)((b * HH + h) * CC) + c) * HD + hd] = val;
                else
                    vtb[((size_t)((b * HH + h) * HD) + hd) * CC + c] = val;
            }
        }
    }
#undef QITER
#undef QSTAGE
#undef SCHED0
}

// ---------------------------------------------------------------------------
// Flash attention v6: cross-tile software pipeline, ROLLED loop + LDS-offset
// rotation. Iter kt: prefetch K/V_{kt+1}; PV_{kt-1} (independent MFMA stream);
// S_kt -> exp -> pack -> P_kt. K dbuf, V triple-buf, P dbuf (wave-private).
// ---------------------------------------------------------------------------
__global__ __launch_bounds__(256)
void attn_mfma6(const ushort* __restrict__ qb, const ushort* __restrict__ kb,
                const ushort* __restrict__ vt, ushort* __restrict__ attnb)
{
    __shared__ ushort lds[2 * 4096 + 3 * 4096 + 2 * 9216];   // 76 KB
    const uint K0 = 0, K1 = 4096;
    const uint V0 = 8192, V1 = 12288, V2 = 16384;
    const uint P0 = 20480, P1 = 29696;

    const int tid = threadIdx.x;
    const int wid = tid >> 6, lane = tid & 63;
    const int quad = lane >> 4, l15 = lane & 15;
    const int bh = blockIdx.x & 63;          // bh-fastest: XCD L2 locality
    const int qt = blockIdx.x >> 6;
    const int q0 = qt * 128;
    const int b = bh >> 4, h = bh & 15;

    const ushort* Qp  = qb + ((size_t)bh * CC + q0) * HD;
    const ushort* Kp  = kb + (size_t)bh * CC * HD;
    const ushort* Vtp = vt + (size_t)bh * HD * CC;

    const int sr = lane >> 3;    // 0..7
    const int sc = lane & 7;     // chunk 0..7

    // Q fragments straight from global: B-operand [n=qrow][k=d], kt-invariant
    short8 qf[2][2];
    #pragma unroll
    for (int q2 = 0; q2 < 2; ++q2) {
        int row = wid * 32 + q2 * 16 + l15;
        #pragma unroll
        for (int s = 0; s < 2; ++s)
            qf[q2][s] = *(const short8*)(Qp + (size_t)row * HD + (s * 4 + quad) * 8);
    }

    // staging addresses (kt-invariant parts)
    const int kr = wid * 16 + sr;            // rows kr, kr+8
    const int cgA = sc ^ (kr & 7);
    const int cgB = sc ^ ((kr + 8) & 7);
    const ushort* Kr0 = Kp  + (size_t)kr * HD + cgA * 8;
    const ushort* Kr1 = Kp  + (size_t)(kr + 8) * HD + cgB * 8;
    const ushort* Vr0 = Vtp + (size_t)kr * CC + cgA * 8;
    const ushort* Vr1 = Vtp + (size_t)(kr + 8) * CC + cgB * 8;

    const uint stg0 = (wid * 16) * 64;       // LDS staging offsets within a buffer
    const uint stg1 = (wid * 16 + 8) * 64;

    // prologue: K_0 -> K0, V_0 -> V0
    glds16(Kr0, lds + K0 + stg0);
    glds16(Kr1, lds + K0 + stg1);
    glds16(Vr0, lds + V0 + stg0);
    glds16(Vr1, lds + V0 + stg1);

    f32x4 oacc[2][4];
    #pragma unroll
    for (int q2 = 0; q2 < 2; ++q2)
        #pragma unroll
        for (int hb = 0; hb < 4; ++hb) oacc[q2][hb] = (f32x4)(0.0f);
    float lsum[2] = {0.0f, 0.0f};

    uint ksC = K0, ksN = K1;
    uint vsP = V2, vsC = V0, vsN = V1;
    uint psC = P0, psP = P1;

    for (int kt = 0; kt < 16; ++kt) {
        __syncthreads();                      // K_kt, V_kt resident
        if (kt < 15) {                        // prefetch K/V_{kt+1}
            const int koff = (kt + 1) * 64;
            glds16(Kr0 + (size_t)koff * HD, lds + ksN + stg0);
            glds16(Kr1 + (size_t)koff * HD, lds + ksN + stg1);
            glds16(Vr0 + koff,              lds + vsN + stg0);
            glds16(Vr1 + koff,              lds + vsN + stg1);
        }

        if (kt > 0) {
            // PV_{kt-1}: O += P_{kt-1} @ V_{kt-1}  (independent of S_kt)
            short8 vf[4][2];
            #pragma unroll
            for (int hb = 0; hb < 4; ++hb) {
                int hr = hb * 16 + l15;
                vf[hb][0] = *(const short8*)(lds + vsP + hr * 64 + ((quad ^ (hr & 7)) * 8));
                vf[hb][1] = *(const short8*)(lds + vsP + hr * 64 + (((4 + quad) ^ (hr & 7)) * 8));
            }
            #pragma unroll
            for (int q2 = 0; q2 < 2; ++q2) {
                int row = wid * 32 + q2 * 16 + l15;
                short8 pf0 = *(const short8*)(lds + psP + row * 72 + quad * 8);
                short8 pf1 = *(const short8*)(lds + psP + row * 72 + 32 + quad * 8);
                #pragma unroll
                for (int hb = 0; hb < 4; ++hb) {
                    oacc[q2][hb] = MFMA16(pf0, vf[hb][0], oacc[q2][hb]);
                    oacc[q2][hb] = MFMA16(pf1, vf[hb][1], oacc[q2][hb]);
                }
            }
        }

        // S_kt = K @ Q^T : lane holds S[qrow=l15][key=kb2*16+quad*4+r]
        #pragma unroll
        for (int kb2 = 0; kb2 < 4; ++kb2) {
            int krow = kb2 * 16 + l15;
            short8 kf0 = *(const short8*)(lds + ksC + krow * 64 + ((quad ^ (krow & 7)) * 8));
            short8 kf1 = *(const short8*)(lds + ksC + krow * 64 + (((4 + quad) ^ (krow & 7)) * 8));
            #pragma unroll
            for (int q2 = 0; q2 < 2; ++q2) {
                f32x4 st = (f32x4)(0.0f);
                st = MFMA16(kf0, qf[q2][0], st);
                st = MFMA16(kf1, qf[q2][1], st);
                float p0 = EXP2(st[0]);
                float p1 = EXP2(st[1]);
                float p2 = EXP2(st[2]);
                float p3 = EXP2(st[3]);
                lsum[q2] += (p0 + p1) + (p2 + p3);
                int row = wid * 32 + q2 * 16 + l15;
                *(uint2*)(lds + psC + row * 72 + kb2 * 16 + quad * 4) =
                    make_uint2(pack2bf(p0, p1), pack2bf(p2, p3));
            }
        }

        // rotate buffers
        uint t = vsP; vsP = vsC; vsC = vsN; vsN = t;
        t = ksC; ksC = ksN; ksN = t;
        t = psP; psP = psC; psC = t;
    }

    // final PV_15: P_15 at psP, V_15 at vsP (post-rotation); no barrier needed
    {
        short8 vf[4][2];
        #pragma unroll
        for (int hb = 0; hb < 4; ++hb) {
            int hr = hb * 16 + l15;
            vf[hb][0] = *(const short8*)(lds + vsP + hr * 64 + ((quad ^ (hr & 7)) * 8));
            vf[hb][1] = *(const short8*)(lds + vsP + hr * 64 + (((4 + quad) ^ (hr & 7)) * 8));
        }
        #pragma unroll
        for (int q2 = 0; q2 < 2; ++q2) {
            int row = wid * 32 + q2 * 16 + l15;
            short8 pf0 = *(const short8*)(lds + psP + row * 72 + quad * 8);
            short8 pf1 = *(const short8*)(lds + psP + row * 72 + 32 + quad * 8);
            #pragma unroll
            for (int hb = 0; hb < 4; ++hb) {
                oacc[q2][hb] = MFMA16(pf0, vf[hb][0], oacc[q2][hb]);
                oacc[q2][hb] = MFMA16(pf1, vf[hb][1], oacc[q2][hb]);
            }
        }
    }

    // reduce lsum across the 4 quads (lanes sharing l15)
    #pragma unroll
    for (int q2 = 0; q2 < 2; ++q2) {
        lsum[q2] += __shfl_xor(lsum[q2], 16);
        lsum[q2] += __shfl_xor(lsum[q2], 32);
    }

    #pragma unroll
    for (int q2 = 0; q2 < 2; ++q2) {
        #pragma unroll
        for (int r = 0; r < 4; ++r) {
            float inv = 1.0f / __shfl(lsum[q2], (lane & 48) | (quad * 4 + r));
            int c = q0 + wid * 32 + q2 * 16 + quad * 4 + r;
            #pragma unroll
            for (int hb = 0; hb < 4; ++hb) {
                int d = h * 64 + hb * 16 + l15;
                attnb[((size_t)(b * CC + c)) * DD + d] = f2bf(oacc[q2][hb][r] * inv);
            }
        }
    }
}

// ---------------------------------------------------------------------------
extern "C" void kernel_launch(void* const* d_in, const int* in_sizes, int n_in,
                              void* d_out, int out_size, void* d_ws, size_t ws_size,
                              hipStream_t stream)
{
    (void)in_sizes; (void)n_in; (void)out_size; (void)ws_size;
    const float* x      = (const float*)d_in[0];
    const float* w_qkv  = (const float*)d_in[1];
    const float* b_qkv  = (const float*)d_in[2];
    const float* w_proj = (const float*)d_in[3];
    const float* b_proj = (const float*)d_in[4];
    float* out = (float*)d_out;

    ushort* p = (ushort*)d_ws;
    ushort* xbf   = p;  p += (size_t)4 * 1024 * 1024;   // x bf16
    ushort* wqkvT = p;  p += (size_t)3 * 1024 * 1024;   // w_qkv^T bf16
    ushort* wprjT = p;  p += (size_t)1 * 1024 * 1024;   // w_proj^T bf16
    ushort* qbuf  = p;  p += (size_t)4 * 1024 * 1024;   // Q (B,H,C,Hd), pre-scaled
    ushort* kbuf  = p;  p += (size_t)4 * 1024 * 1024;   // K (B,H,C,Hd)
    ushort* vtb   = p;  p += (size_t)4 * 1024 * 1024;   // V^T (B,H,Hd,C)
    ushort* attnb = p;  p += (size_t)4 * 1024 * 1024;   // attention out (B,C,D)

    prep_kernel<<<5120, 256, 0, stream>>>(x, xbf, w_qkv, wqkvT, w_proj, wprjT);

    // QKV: 256x256 tile, 8 waves, 4-phase interleave + counted vmcnt; 12x16=192
    gemm_qkv256<<<dim3(NH3 / 256, (BB * CC) / 256), 512, 0, stream>>>(
        xbf, wqkvT, b_qkv, qbuf, kbuf, vtb);

    attn_mfma6<<<512, 256, 0, stream>>>(qbuf, kbuf, vtb, attnb);

    // proj: M-tile 64 -> 512 blocks (2 blocks/CU) for latency hiding
    gemm_bt<0, 64><<<dim3(DD / 128, (BB * CC) / 64), 256, 0, stream>>>(
        attnb, wprjT, b_proj, out, nullptr, nullptr, nullptr, BB * CC, DD, DD);
}

// Round 3
// 176.450 us; speedup vs baseline: 1.0918x; 1.0822x over previous
//
#include <hip/hip_runtime.h>
#include <cstdint>

#define BB 4
#define CC 1024
#define DD 1024
#define HH 16
#define HD 64
#define NH3 3072

typedef __attribute__((ext_vector_type(8))) short short8;   // 8 x bf16 (4 VGPRs)
typedef __attribute__((ext_vector_type(4))) float f32x4;

#define MFMA16(a, b, c) __builtin_amdgcn_mfma_f32_16x16x32_bf16(a, b, c, 0, 0, 0)
#define EXP2 __builtin_amdgcn_exp2f

// async global->LDS, 16B per lane; LDS dest = uniform base + lane*16
__device__ __forceinline__ void glds16(const void* g, void* l) {
    __builtin_amdgcn_global_load_lds(
        (const __attribute__((address_space(1))) void*)g,
        (__attribute__((address_space(3))) void*)l, 16, 0, 0);
}

__device__ __forceinline__ ushort f2bf(float f) {
    union { float f; uint32_t u; } v; v.f = f;
    uint32_t r = v.u + 0x7FFF + ((v.u >> 16) & 1);   // round-to-nearest-even
    return (ushort)(r >> 16);
}

// pack two fp32 -> bf16x2 via v_perm_b32
__device__ __forceinline__ uint32_t pack2bf(float a, float b) {
    uint32_t ua = __float_as_uint(a), ub = __float_as_uint(b);
    ua += 0x7FFF + ((ua >> 16) & 1);
    ub += 0x7FFF + ((ub >> 16) & 1);
    return __builtin_amdgcn_perm(ua, ub, 0x03020706);  // lo16=bf(a), hi16=bf(b)
}

// ---------------------------------------------------------------------------
// prep: fused x->bf16 convert + w_qkv^T + w_proj^T (one launch)
// ---------------------------------------------------------------------------
__global__ __launch_bounds__(256)
void prep_kernel(const float* __restrict__ x, ushort* __restrict__ xbf,
                 const float* __restrict__ wqkv, ushort* __restrict__ wqkvT,
                 const float* __restrict__ wprj, ushort* __restrict__ wprjT)
{
    __shared__ float Ts[64 * 65];
    const int blk = blockIdx.x;
    const int t = threadIdx.x;

    if (blk < 4096) {
        int i = blk * 256 + t;
        float4 v = ((const float4*)x)[i];
        ushort4 o;
        o.x = f2bf(v.x); o.y = f2bf(v.y); o.z = f2bf(v.z); o.w = f2bf(v.w);
        ((ushort4*)xbf)[i] = o;
        return;
    }

    const float* in; ushort* outp; int K, N, n0, k0;
    if (blk < 4864) {
        int bx = blk - 4096;
        in = wqkv; outp = wqkvT; K = DD; N = NH3;
        n0 = (bx % 48) * 64; k0 = (bx / 48) * 64;
    } else {
        int bx = blk - 4864;
        in = wprj; outp = wprjT; K = DD; N = DD;
        n0 = (bx % 16) * 64; k0 = (bx / 16) * 64;
    }
    #pragma unroll
    for (int i = 0; i < 16; ++i) {
        int idx = t + i * 256;
        int r = idx >> 6, c = idx & 63;
        Ts[r * 65 + c] = in[(size_t)(k0 + r) * N + n0 + c];
    }
    __syncthreads();
    #pragma unroll
    for (int i = 0; i < 16; ++i) {
        int idx = t + i * 256;
        int rr = idx >> 6, cc = idx & 63;
        outp[(size_t)(n0 + rr) * K + k0 + cc] = f2bf(Ts[cc * 65 + rr]);
    }
}

// ---------------------------------------------------------------------------
// bf16 MFMA GEMM: MT x 128 tile, BK=32, 3-deep LDS ring + COUNTED vmcnt (T4).
// Stage tile kt+2 while computing kt. Iter top: s_waitcnt vmcnt(L) (tile kt
// resident; kt+1's L loads per wave stay in flight) + raw s_barrier -- never
// drains the global_load_lds queue mid-loop (the ~20%+ stall of the old
// __syncthreads structure). WAR safety: tile kt+2 overwrites buf[(kt-1)%3],
// whose ds_reads were register-consumed before any wave passed barrier kt.
// MT=128: 4 waves 2x2, wave tile 64x64 (4x4 MFMA), L=4, LDS 48KB (3 blk/CU).
// MT=64 : 4 waves 2x2, wave tile 32x64 (2x4 MFMA), L=3, LDS 36KB (2 blk/CU).
// MODE 0: fp32 out + bias.  MODE 1: QKV scatter, V transposed.
// ---------------------------------------------------------------------------
template<int MODE, int MT>
__global__ __launch_bounds__(256)
void gemm_bt(const ushort* __restrict__ A, const ushort* __restrict__ Bt,
             const float* __restrict__ bias, float* __restrict__ Cf,
             ushort* __restrict__ qb, ushort* __restrict__ kb, ushort* __restrict__ vtb,
             int M, int N, int K)
{
    constexpr int MI = MT / 32;               // M-dir MFMA tiles per wave
    __shared__ ushort As[3][MT * 32];
    __shared__ ushort Bs[3][128 * 32];

    const int tid = threadIdx.x;
    const int wid = tid >> 6, lane = tid & 63;
    const int quad = lane >> 4, l15 = lane & 15;
    const int m0 = blockIdx.y * MT, n0 = blockIdx.x * 128;
    const int wm = (wid >> 1) * (MT / 2), wn = (wid & 1) * 64;

    const int sr = lane >> 2;
    const int sc = lane & 3;

    // A staging: wave stages MT/4 rows (16 rows per glds)
    const int ar0 = wid * (MT / 4) + sr;
    const int acg0 = sc ^ ((ar0 >> 1) & 3);
    const int acg1 = sc ^ (((ar0 + 16) >> 1) & 3);
    const ushort* Ar0 = A + (size_t)(m0 + ar0) * K + acg0 * 8;
    const ushort* Ar1 = A + (size_t)(m0 + ar0 + 16) * K + acg1 * 8;   // MT=128 only
    // B staging: 128 rows, 2 glds per wave
    const int br0 = wid * 32 + sr;
    const int bcg0 = sc ^ ((br0 >> 1) & 3);
    const int bcg1 = sc ^ (((br0 + 16) >> 1) & 3);
    const ushort* Br0 = Bt + (size_t)(n0 + br0) * K + bcg0 * 8;
    const ushort* Br1 = Bt + (size_t)(n0 + br0 + 16) * K + bcg1 * 8;

    f32x4 acc[MI][4];
    #pragma unroll
    for (int i = 0; i < MI; ++i)
        #pragma unroll
        for (int j = 0; j < 4; ++j) acc[i][j] = (f32x4)(0.0f);

#define GSTAGE(kn, bidx) do { \
        glds16(Ar0 + (kn), &As[bidx][(wid * (MT / 4)) * 32]); \
        glds16(Br0 + (kn), &Bs[bidx][(wid * 32) * 32]); \
        if (MT == 128) glds16(Ar1 + (kn), &As[bidx][(wid * 32 + 16) * 32]); \
        glds16(Br1 + (kn), &Bs[bidx][(wid * 32 + 16) * 32]); } while (0)

    // prologue: stage tiles 0 and 1 (2L loads per wave in flight)
    GSTAGE(0, 0);
    GSTAGE(32, 1);

    int cur = 0;
    for (int k0 = 0; k0 < K; k0 += 32) {
        // counted wait: tile k0 resident everywhere; next tile stays in flight
        if (k0 + 32 < K) {
            if (MT == 128)
                asm volatile("s_waitcnt vmcnt(4)\n\ts_barrier" ::: "memory");
            else
                asm volatile("s_waitcnt vmcnt(3)\n\ts_barrier" ::: "memory");
        } else {
            asm volatile("s_waitcnt vmcnt(0)\n\ts_barrier" ::: "memory");
        }
        if (k0 + 64 < K) {
            const int nb = (cur >= 1) ? cur - 1 : 2;    // (cur+2) % 3
            GSTAGE(k0 + 64, nb);
        }

        short8 af[MI], bf[4];
        #pragma unroll
        for (int i = 0; i < MI; ++i) {
            int row = wm + i * 16 + l15;
            af[i] = *(const short8*)(&As[cur][row * 32 + (quad ^ ((row >> 1) & 3)) * 8]);
        }
        #pragma unroll
        for (int j = 0; j < 4; ++j) {
            int col = wn + j * 16 + l15;
            bf[j] = *(const short8*)(&Bs[cur][col * 32 + (quad ^ ((col >> 1) & 3)) * 8]);
        }
        #pragma unroll
        for (int i = 0; i < MI; ++i)
            #pragma unroll
            for (int j = 0; j < 4; ++j)
                acc[i][j] = MFMA16(af[i], bf[j], acc[i][j]);

        cur = (cur == 2) ? 0 : cur + 1;
    }
#undef GSTAGE

    if (MODE == 0) {
        #pragma unroll
        for (int i = 0; i < MI; ++i) {
            int row = m0 + wm + i * 16 + quad * 4;
            #pragma unroll
            for (int j = 0; j < 4; ++j) {
                int col = n0 + wn + j * 16 + l15;
                float bv = bias[col];
                #pragma unroll
                for (int r = 0; r < 4; ++r)
                    Cf[(size_t)(row + r) * N + col] = acc[i][j][r] + bv;
            }
        }
    } else {
        #pragma unroll
        for (int j = 0; j < 4; ++j) {
            int n = n0 + wn + j * 16 + l15;
            int three = n >> 10;
            int h = (n >> 6) & 15;
            int hd = n & 63;
            float scale = (three == 0) ? 0.1803368801f : 1.0f;  // 0.125*log2(e)
            float bv = bias[n];
            #pragma unroll
            for (int i = 0; i < MI; ++i) {
                int row = m0 + wm + i * 16 + quad * 4;
                #pragma unroll
                for (int r = 0; r < 4; ++r) {
                    int m = row + r;
                    int b = m >> 10, c = m & 1023;
                    ushort val = f2bf((acc[i][j][r] + bv) * scale);
                    if (three == 0)
                        qb[((size_t)((b * HH + h) * CC) + c) * HD + hd] = val;
                    else if (three == 1)
                        kb[((size_t)((b * HH + h) * CC) + c) * HD + hd] = val;
                    else
                        vtb[((size_t)((b * HH + h) * HD) + hd) * CC + c] = val;
                }
            }
        }
    }
}

// ---------------------------------------------------------------------------
// Flash attention v6: cross-tile software pipeline, ROLLED loop + LDS-offset
// rotation. Iter kt: prefetch K/V_{kt+1}; PV_{kt-1} (independent MFMA stream);
// S_kt -> exp -> pack -> P_kt. K dbuf, V triple-buf, P dbuf (wave-private).
// ---------------------------------------------------------------------------
__global__ __launch_bounds__(256)
void attn_mfma6(const ushort* __restrict__ qb, const ushort* __restrict__ kb,
                const ushort* __restrict__ vt, ushort* __restrict__ attnb)
{
    __shared__ ushort lds[2 * 4096 + 3 * 4096 + 2 * 9216];   // 76 KB
    const uint K0 = 0, K1 = 4096;
    const uint V0 = 8192, V1 = 12288, V2 = 16384;
    const uint P0 = 20480, P1 = 29696;

    const int tid = threadIdx.x;
    const int wid = tid >> 6, lane = tid & 63;
    const int quad = lane >> 4, l15 = lane & 15;
    const int bh = blockIdx.x & 63;          // bh-fastest: XCD L2 locality
    const int qt = blockIdx.x >> 6;
    const int q0 = qt * 128;
    const int b = bh >> 4, h = bh & 15;

    const ushort* Qp  = qb + ((size_t)bh * CC + q0) * HD;
    const ushort* Kp  = kb + (size_t)bh * CC * HD;
    const ushort* Vtp = vt + (size_t)bh * HD * CC;

    const int sr = lane >> 3;    // 0..7
    const int sc = lane & 7;     // chunk 0..7

    // Q fragments straight from global: B-operand [n=qrow][k=d], kt-invariant
    short8 qf[2][2];
    #pragma unroll
    for (int q2 = 0; q2 < 2; ++q2) {
        int row = wid * 32 + q2 * 16 + l15;
        #pragma unroll
        for (int s = 0; s < 2; ++s)
            qf[q2][s] = *(const short8*)(Qp + (size_t)row * HD + (s * 4 + quad) * 8);
    }

    // staging addresses (kt-invariant parts)
    const int kr = wid * 16 + sr;            // rows kr, kr+8
    const int cgA = sc ^ (kr & 7);
    const int cgB = sc ^ ((kr + 8) & 7);
    const ushort* Kr0 = Kp  + (size_t)kr * HD + cgA * 8;
    const ushort* Kr1 = Kp  + (size_t)(kr + 8) * HD + cgB * 8;
    const ushort* Vr0 = Vtp + (size_t)kr * CC + cgA * 8;
    const ushort* Vr1 = Vtp + (size_t)(kr + 8) * CC + cgB * 8;

    const uint stg0 = (wid * 16) * 64;       // LDS staging offsets within a buffer
    const uint stg1 = (wid * 16 + 8) * 64;

    // prologue: K_0 -> K0, V_0 -> V0
    glds16(Kr0, lds + K0 + stg0);
    glds16(Kr1, lds + K0 + stg1);
    glds16(Vr0, lds + V0 + stg0);
    glds16(Vr1, lds + V0 + stg1);

    f32x4 oacc[2][4];
    #pragma unroll
    for (int q2 = 0; q2 < 2; ++q2)
        #pragma unroll
        for (int hb = 0; hb < 4; ++hb) oacc[q2][hb] = (f32x4)(0.0f);
    float lsum[2] = {0.0f, 0.0f};

    uint ksC = K0, ksN = K1;
    uint vsP = V2, vsC = V0, vsN = V1;
    uint psC = P0, psP = P1;

    for (int kt = 0; kt < 16; ++kt) {
        __syncthreads();                      // K_kt, V_kt resident
        if (kt < 15) {                        // prefetch K/V_{kt+1}
            const int koff = (kt + 1) * 64;
            glds16(Kr0 + (size_t)koff * HD, lds + ksN + stg0);
            glds16(Kr1 + (size_t)koff * HD, lds + ksN + stg1);
            glds16(Vr0 + koff,              lds + vsN + stg0);
            glds16(Vr1 + koff,              lds + vsN + stg1);
        }

        if (kt > 0) {
            // PV_{kt-1}: O += P_{kt-1} @ V_{kt-1}  (independent of S_kt)
            short8 vf[4][2];
            #pragma unroll
            for (int hb = 0; hb < 4; ++hb) {
                int hr = hb * 16 + l15;
                vf[hb][0] = *(const short8*)(lds + vsP + hr * 64 + ((quad ^ (hr & 7)) * 8));
                vf[hb][1] = *(const short8*)(lds + vsP + hr * 64 + (((4 + quad) ^ (hr & 7)) * 8));
            }
            #pragma unroll
            for (int q2 = 0; q2 < 2; ++q2) {
                int row = wid * 32 + q2 * 16 + l15;
                short8 pf0 = *(const short8*)(lds + psP + row * 72 + quad * 8);
                short8 pf1 = *(const short8*)(lds + psP + row * 72 + 32 + quad * 8);
                #pragma unroll
                for (int hb = 0; hb < 4; ++hb) {
                    oacc[q2][hb] = MFMA16(pf0, vf[hb][0], oacc[q2][hb]);
                    oacc[q2][hb] = MFMA16(pf1, vf[hb][1], oacc[q2][hb]);
                }
            }
        }

        // S_kt = K @ Q^T : lane holds S[qrow=l15][key=kb2*16+quad*4+r]
        #pragma unroll
        for (int kb2 = 0; kb2 < 4; ++kb2) {
            int krow = kb2 * 16 + l15;
            short8 kf0 = *(const short8*)(lds + ksC + krow * 64 + ((quad ^ (krow & 7)) * 8));
            short8 kf1 = *(const short8*)(lds + ksC + krow * 64 + (((4 + quad) ^ (krow & 7)) * 8));
            #pragma unroll
            for (int q2 = 0; q2 < 2; ++q2) {
                f32x4 st = (f32x4)(0.0f);
                st = MFMA16(kf0, qf[q2][0], st);
                st = MFMA16(kf1, qf[q2][1], st);
                float p0 = EXP2(st[0]);
                float p1 = EXP2(st[1]);
                float p2 = EXP2(st[2]);
                float p3 = EXP2(st[3]);
                lsum[q2] += (p0 + p1) + (p2 + p3);
                int row = wid * 32 + q2 * 16 + l15;
                *(uint2*)(lds + psC + row * 72 + kb2 * 16 + quad * 4) =
                    make_uint2(pack2bf(p0, p1), pack2bf(p2, p3));
            }
        }

        // rotate buffers
        uint t = vsP; vsP = vsC; vsC = vsN; vsN = t;
        t = ksC; ksC = ksN; ksN = t;
        t = psP; psP = psC; psC = t;
    }

    // final PV_15: P_15 at psP, V_15 at vsP (post-rotation); no barrier needed
    {
        short8 vf[4][2];
        #pragma unroll
        for (int hb = 0; hb < 4; ++hb) {
            int hr = hb * 16 + l15;
            vf[hb][0] = *(const short8*)(lds + vsP + hr * 64 + ((quad ^ (hr & 7)) * 8));
            vf[hb][1] = *(const short8*)(lds + vsP + hr * 64 + (((4 + quad) ^ (hr & 7)) * 8));
        }
        #pragma unroll
        for (int q2 = 0; q2 < 2; ++q2) {
            int row = wid * 32 + q2 * 16 + l15;
            short8 pf0 = *(const short8*)(lds + psP + row * 72 + quad * 8);
            short8 pf1 = *(const short8*)(lds + psP + row * 72 + 32 + quad * 8);
            #pragma unroll
            for (int hb = 0; hb < 4; ++hb) {
                oacc[q2][hb] = MFMA16(pf0, vf[hb][0], oacc[q2][hb]);
                oacc[q2][hb] = MFMA16(pf1, vf[hb][1], oacc[q2][hb]);
            }
        }
    }

    // reduce lsum across the 4 quads (lanes sharing l15)
    #pragma unroll
    for (int q2 = 0; q2 < 2; ++q2) {
        lsum[q2] += __shfl_xor(lsum[q2], 16);
        lsum[q2] += __shfl_xor(lsum[q2], 32);
    }

    #pragma unroll
    for (int q2 = 0; q2 < 2; ++q2) {
        #pragma unroll
        for (int r = 0; r < 4; ++r) {
            float inv = 1.0f / __shfl(lsum[q2], (lane & 48) | (quad * 4 + r));
            int c = q0 + wid * 32 + q2 * 16 + quad * 4 + r;
            #pragma unroll
            for (int hb = 0; hb < 4; ++hb) {
                int d = h * 64 + hb * 16 + l15;
                attnb[((size_t)(b * CC + c)) * DD + d] = f2bf(oacc[q2][hb][r] * inv);
            }
        }
    }
}

// ---------------------------------------------------------------------------
extern "C" void kernel_launch(void* const* d_in, const int* in_sizes, int n_in,
                              void* d_out, int out_size, void* d_ws, size_t ws_size,
                              hipStream_t stream)
{
    (void)in_sizes; (void)n_in; (void)out_size; (void)ws_size;
    const float* x      = (const float*)d_in[0];
    const float* w_qkv  = (const float*)d_in[1];
    const float* b_qkv  = (const float*)d_in[2];
    const float* w_proj = (const float*)d_in[3];
    const float* b_proj = (const float*)d_in[4];
    float* out = (float*)d_out;

    ushort* p = (ushort*)d_ws;
    ushort* xbf   = p;  p += (size_t)4 * 1024 * 1024;   // x bf16
    ushort* wqkvT = p;  p += (size_t)3 * 1024 * 1024;   // w_qkv^T bf16
    ushort* wprjT = p;  p += (size_t)1 * 1024 * 1024;   // w_proj^T bf16
    ushort* qbuf  = p;  p += (size_t)4 * 1024 * 1024;   // Q (B,H,C,Hd), pre-scaled
    ushort* kbuf  = p;  p += (size_t)4 * 1024 * 1024;   // K (B,H,C,Hd)
    ushort* vtb   = p;  p += (size_t)4 * 1024 * 1024;   // V^T (B,H,Hd,C)
    ushort* attnb = p;  p += (size_t)4 * 1024 * 1024;   // attention out (B,C,D)

    prep_kernel<<<5120, 256, 0, stream>>>(x, xbf, w_qkv, wqkvT, w_proj, wprjT);

    // QKV: 128x128 tile, 768 blocks (3/CU), 3-ring counted-vmcnt pipeline
    gemm_bt<1, 128><<<dim3(NH3 / 128, (BB * CC) / 128), 256, 0, stream>>>(
        xbf, wqkvT, b_qkv, nullptr, qbuf, kbuf, vtb, BB * CC, NH3, DD);

    attn_mfma6<<<512, 256, 0, stream>>>(qbuf, kbuf, vtb, attnb);

    // proj: M-tile 64 -> 512 blocks (2 blocks/CU), same 3-ring pipeline
    gemm_bt<0, 64><<<dim3(DD / 128, (BB * CC) / 64), 256, 0, stream>>>(
        attnb, wprjT, b_proj, out, nullptr, nullptr, nullptr, BB * CC, DD, DD);
}